// Round 5
// baseline (297.689 us; speedup 1.0000x reference)
//
#include <hip/hip_runtime.h>
#include <cstdint>
#include <cstddef>

#define CIN   128
#define COUT  256
#define HW    64
#define NSP   4096      // 64*64 spatial
#define KTOT  1152      // CIN*9
#define BATCH 32
#define PDROP 0.2f
#define LDT   40        // fallback conv LDS stride (bf16 elems)

__device__ __forceinline__ unsigned short f2bf(float f) {
    unsigned int u = __builtin_bit_cast(unsigned int, f);
    u += 0x7fffu + ((u >> 16) & 1u);   // round-to-nearest-even
    return (unsigned short)(u >> 16);
}

// 128 B of guaranteed zeros for OOB halo DMA source (never written)
__device__ __align__(16) unsigned short g_zeros[64] = {0};

// async global->LDS, 16 B per lane; LDS dest = wave-uniform base + lane*16
__device__ __forceinline__ void gl_lds16(const unsigned short* g, unsigned short* l) {
    __builtin_amdgcn_global_load_lds(
        (const __attribute__((address_space(1))) unsigned int*)g,
        (__attribute__((address_space(3))) unsigned int*)l,
        16, 0, 0);
}

// ---------------------------------------------------------------------------
// Fused pre-pass (single launch):
//  blocks [0,1024):    masked bf16 weights into A-fragment-major layout
//                      wt2[b][mt][tap][slab][chunk8][row128][8ch]
//                      block = (b, mt, rowgroup rg of 8 rows)
//  blocks [1024,3072): x NCHW fp32 -> xt[b][hw][ch] bf16 (NHWC)
__global__ __launch_bounds__(256) void prepass(
        const float* __restrict__ weight, const float* __restrict__ u_w,
        const float* __restrict__ x,
        unsigned short* __restrict__ wt2, unsigned short* __restrict__ xt)
{
    __shared__ unsigned short sh[9280];            // max(8*1160, 64*136)
    const int t = threadIdx.x;

    if (blockIdx.x < 1024) {
        const int bw = blockIdx.x;
        const int rg = bw & 15;                    // row-group (8 rows)
        const int mt = (bw >> 4) & 1;              // m-tile
        const int b  = bw >> 5;                    // sample
        const int o0 = mt * 128 + rg * 8;

        // ---- load + mask + scatter to LDS stile[bo_loc(8)][tap(9)][i(128)]
        // stile row stride 1160 (pad 8) to kill write-out bank conflicts
        #pragma unroll
        for (int j = 0; j < 9; ++j) {
            const int idx = j * 256 + t;           // 0..2303 float4s
            const int bo_loc = idx / 288;
            const int rem    = idx - bo_loc * 288;
            const int o  = o0 + bo_loc;
            const float4 wv = reinterpret_cast<const float4*>(
                weight + (size_t)o * KTOT)[rem];
            const float4 uv = reinterpret_cast<const float4*>(
                u_w + (size_t)(b * COUT + o) * KTOT)[rem];
            const float w4[4] = {wv.x, wv.y, wv.z, wv.w};
            const float u4[4] = {uv.x, uv.y, uv.z, uv.w};
            #pragma unroll
            for (int c = 0; c < 4; ++c) {
                const int ks  = rem * 4 + c;       // = i*9 + tap
                const int i   = ks / 9;
                const int tap = ks - 9 * i;
                sh[bo_loc * 1160 + tap * CIN + i] =
                    f2bf((u4[c] > PDROP) ? w4[c] : 0.f);
            }
        }
        __syncthreads();

        // ---- write out: per (tap,slab,chunk): 8 rows x 16 B
        unsigned short* dstb = wt2 + ((size_t)(b * 2 + mt) * 18) * 8192;
        #pragma unroll
        for (int j = 0; j < 5; ++j) {
            const int g = j * 256 + t;             // 0..1151 uint4 granules
            if (g < 1152) {
                const int row_loc = g & 7;
                const int tsc     = g >> 3;        // 0..143 = tap*16+slab*8+chunk
                const int tap   = tsc >> 4;
                const int slab  = (tsc >> 3) & 1;
                const int chunk = tsc & 7;
                const uint4 v = *reinterpret_cast<const uint4*>(
                    &sh[row_loc * 1160 + tap * CIN + slab * 64 + chunk * 8]);
                *reinterpret_cast<uint4*>(
                    dstb + (size_t)(tap * 2 + slab) * 8192 + chunk * 1024
                         + (rg * 8 + row_loc) * 8) = v;
            }
        }
    } else {
        const int bidx = blockIdx.x - 1024;
        const int b    = bidx >> 6;
        const int hw0  = (bidx & 63) * 64;
        const int ib   = t >> 4;                   // 0..15
        const int hw4  = (t & 15) * 4;
        #pragma unroll
        for (int j = 0; j < 8; ++j) {
            const int i = ib + 16 * j;             // channel 0..127
            const float4 v = *reinterpret_cast<const float4*>(
                x + ((size_t)(b * CIN + i)) * NSP + hw0 + hw4);
            const float v4[4] = {v.x, v.y, v.z, v.w};
            #pragma unroll
            for (int c = 0; c < 4; ++c)
                sh[(hw4 + c) * 136 + i] = f2bf(v4[c]);
        }
        __syncthreads();
        #pragma unroll
        for (int j = 0; j < 4; ++j) {
            const int idx  = j * 256 + t;          // 0..1023
            const int row  = idx >> 4;             // hw_loc 0..63
            const int part = idx & 15;             // 16 B chunk
            const uint4 v = *reinterpret_cast<const uint4*>(&sh[row * 136 + part * 8]);
            *reinterpret_cast<uint4*>(
                xt + ((size_t)(b * NSP + hw0 + row)) * CIN + part * 8) = v;
        }
    }
}

// ---------------------------------------------------------------------------
// Main conv v5: implicit GEMM, LDS-resident x-tile, A-fragments loaded
// DIRECTLY global->VGPR from fragment-major wt2 (no A LDS, no per-tap
// barriers). Per ch-slab: stage X[4rows][66cols][64ch] once, then 9 taps of
// {8 coalesced A-frag loads + 8 B-frag ds_read_b128 + 32 MFMA}, barrier-free.
__global__ __launch_bounds__(256, 3) void conv_v5(
        const unsigned short* __restrict__ wt2,
        const unsigned short* __restrict__ xt,
        const float* __restrict__ bias, const float* __restrict__ u_b,
        float* __restrict__ out)
{
    using frag  = __attribute__((ext_vector_type(8))) short;
    using f32x4 = __attribute__((ext_vector_type(4))) float;

    __shared__ unsigned short Xs[4 * 66 * 64];     // 33792 B resident x-tile

    const int tid  = threadIdx.x;
    const int lane = tid & 63;
    const int q    = lane >> 4;
    const int l15  = lane & 15;
    const int wv   = tid >> 6;
    const int wm   = (wv >> 1) * 64;
    const int wn   = (wv & 1) * 64;
    const int wnrow = wn >> 6;                     // 0/1: tile spatial row

    const int b   = blockIdx.z;
    const int m0  = blockIdx.y * 128;
    const int n0  = blockIdx.x * 128;
    const int ph0 = n0 >> 6;                       // first global image row

    const unsigned short* xtb = xt + (size_t)b * NSP * CIN;

    // ---- A-frag base: wt2[b][mt] + lane-constant (row,chunk) offset.
    // Load for (s2,tap,ki,mi): base + (tap*2+s2)*8192 + ki*4096 + mi*128
    const unsigned short* a_bm = wt2
        + (size_t)(b * 2 + (m0 >> 7)) * 147456     // 18*8192
        + (size_t)(wm + l15) * 8 + q * 1024;

    // ---- X-DMA map: wave wv stages X row rr=wv (global row ph0-1+wv)
    const int kcl = (lane & 7) ^ ((1 + (lane >> 3)) & 7);
    const int xsrc_lane = (lane >> 3) * CIN + kcl * 8;
    const int hhx = ph0 - 1 + wv;
    const bool vrow = ((unsigned)hhx < 64u);
    unsigned short* const xdst = &Xs[(wv * 66 + 1) * 64];

    // ---- B-frag read constants (XOR chunk swizzle)
    int xoff[4];
    #pragma unroll
    for (int ni = 0; ni < 4; ++ni) xoff[ni] = (ni * 16 + l15 + 1) * 64;
    int xr[3][2];
    #pragma unroll
    for (int dxi = 0; dxi < 3; ++dxi)
        #pragma unroll
        for (int ki = 0; ki < 2; ++ki)
            xr[dxi][ki] = ((ki * 4 + q) ^ ((l15 + dxi) & 7)) * 8;

    f32x4 acc[4][4];
    #pragma unroll
    for (int i = 0; i < 4; ++i)
        #pragma unroll
        for (int j = 0; j < 4; ++j)
            acc[i][j] = (f32x4){0.f, 0.f, 0.f, 0.f};

    // ---- zero the column-halo cells of Xs (cc=0 and cc=65, all 4 rows)
    {
        const int cell = tid >> 5;                 // 0..7
        const int rr   = cell >> 1;
        const int cc   = (cell & 1) ? 65 : 0;
        *reinterpret_cast<unsigned int*>(
            &Xs[(rr * 66 + cc) * 64 + (tid & 31) * 2]) = 0u;
    }

    #pragma unroll
    for (int s2 = 0; s2 < 2; ++s2) {
        const int i0 = s2 * 64;                    // channel-slab base

        __syncthreads();                           // protect Xs from prior reads

        // ---- X-tile DMA: 8 x 1KB per wave
        {
            const unsigned short* sx = vrow
                ? xtb + (size_t)hhx * HW * CIN + i0 + xsrc_lane
                : g_zeros;
            #pragma unroll
            for (int g = 0; g < 8; ++g)
                gl_lds16(vrow ? (sx + g * 8 * CIN) : sx, xdst + g * 512);
        }

        __syncthreads();                           // drain DMA: Xs ready

        #pragma unroll
        for (int tap = 0; tap < 9; ++tap) {
            const int dy  = tap / 3 - 1;
            const int dx  = tap - 3 * (tap / 3) - 1;
            const int dxi = dx + 1;
            const unsigned short* at = a_bm + (size_t)(tap * 2 + s2) * 8192;
            const int cb = (wnrow + dy + 1) * 4224 + dx * 64;  // 66*64=4224

            #pragma unroll
            for (int ki = 0; ki < 2; ++ki) {
                frag af[4], bfr[4];
                #pragma unroll
                for (int mi = 0; mi < 4; ++mi)
                    af[mi] = *reinterpret_cast<const frag*>(
                        at + ki * 4096 + mi * 128);
                #pragma unroll
                for (int ni = 0; ni < 4; ++ni)
                    bfr[ni] = *reinterpret_cast<const frag*>(
                        &Xs[cb + xoff[ni] + xr[dxi][ki]]);
                #pragma unroll
                for (int mi = 0; mi < 4; ++mi)
                    #pragma unroll
                    for (int ni = 0; ni < 4; ++ni)
                        acc[mi][ni] = __builtin_amdgcn_mfma_f32_16x16x32_bf16(
                            af[mi], bfr[ni], acc[mi][ni], 0, 0, 0);
            }
        }
    }

    // ---- epilogue: D row=(q*4+reg), col=l15 ; add dropped-out bias
    float* ob = out + (size_t)b * COUT * NSP;
    #pragma unroll
    for (int mi = 0; mi < 4; ++mi) {
        #pragma unroll
        for (int rg = 0; rg < 4; ++rg) {
            const int o  = m0 + wm + mi * 16 + q * 4 + rg;
            const float bvv = (u_b[b * COUT + o] > PDROP) ? bias[o] : 0.f;
            float* orow = ob + (size_t)o * NSP + n0 + wn + l15;
            #pragma unroll
            for (int ni = 0; ni < 4; ++ni)
                orow[ni * 16] = acc[mi][ni][rg] + bvv;
        }
    }
}

// ---------------------------------------------------------------------------
// Fallback (round-1 kernel): used only if workspace is too small.
__global__ __launch_bounds__(256) void conv_fb(
        const float* __restrict__ x, const float* __restrict__ weight,
        const float* __restrict__ bias, const float* __restrict__ u_w,
        const float* __restrict__ u_b, float* __restrict__ out)
{
    using frag  = __attribute__((ext_vector_type(8))) short;
    using f32x4 = __attribute__((ext_vector_type(4))) float;

    __shared__ unsigned short As[128 * LDT];
    __shared__ unsigned short Bs[128 * LDT];

    const int tid  = threadIdx.x;
    const int lane = tid & 63;
    const int q    = lane >> 4;
    const int l15  = lane & 15;
    const int wv   = tid >> 6;
    const int wm   = (wv >> 1) * 64;
    const int wn   = (wv & 1) * 64;

    const int b  = blockIdx.z;
    const int m0 = blockIdx.y * 128;
    const int n0 = blockIdx.x * 128;

    const int arow = tid >> 1;
    const int acol = (tid & 1) * 16;
    const int pn = tid & 127;
    const int kh = (tid >> 7) * 16;
    const int p  = n0 + pn;
    const int ph = p >> 6;
    const int pw = p & 63;

    const float* xb = x + (size_t)b * CIN * NSP;

    f32x4 acc[4][4];
    #pragma unroll
    for (int i = 0; i < 4; ++i)
        #pragma unroll
        for (int j = 0; j < 4; ++j)
            acc[i][j] = (f32x4){0.f, 0.f, 0.f, 0.f};

    const int a_rd = (wm + l15) * LDT + q * 8;
    const int b_rd = (wn + l15) * LDT + q * 8;

    for (int s = 0; s < 36; ++s) {
        const int r  = s >> 2;
        const int i0 = (s & 3) * 32;

        float aw[16], au[16];
        {
            const float* wsrc = weight + (size_t)(m0 + arow) * KTOT;
            const float* usrc = u_w + (size_t)(b * COUT + m0 + arow) * KTOT;
            #pragma unroll
            for (int ii = 0; ii < 16; ++ii) {
                const int kk = (i0 + acol + ii) * 9 + r;
                aw[ii] = wsrc[kk];
                au[ii] = usrc[kk];
            }
        }

        const int hh = ph + (r / 3) - 1;
        const int ww = pw + (r % 3) - 1;
        float bx[16];
        #pragma unroll
        for (int j = 0; j < 16; ++j) bx[j] = 0.f;
        if (((unsigned)hh < 64u) && ((unsigned)ww < 64u)) {
            const float* xsrc = xb + (size_t)(i0 + kh) * NSP + hh * HW + ww;
            #pragma unroll
            for (int j = 0; j < 16; ++j) bx[j] = xsrc[(size_t)j * NSP];
        }

        __syncthreads();

        {
            union { unsigned short u16[16]; uint4 v[2]; } tu;
            #pragma unroll
            for (int ii = 0; ii < 16; ++ii)
                tu.u16[ii] = f2bf((au[ii] > PDROP) ? aw[ii] : 0.f);
            uint4* d = reinterpret_cast<uint4*>(&As[arow * LDT + acol]);
            d[0] = tu.v[0]; d[1] = tu.v[1];
        }
        {
            union { unsigned short u16[16]; uint4 v[2]; } tu;
            #pragma unroll
            for (int j = 0; j < 16; ++j) tu.u16[j] = f2bf(bx[j]);
            uint4* d = reinterpret_cast<uint4*>(&Bs[pn * LDT + kh]);
            d[0] = tu.v[0]; d[1] = tu.v[1];
        }

        __syncthreads();

        frag af[4], bfr[4];
        #pragma unroll
        for (int mi = 0; mi < 4; ++mi)
            af[mi] = *reinterpret_cast<const frag*>(&As[a_rd + mi * 16 * LDT]);
        #pragma unroll
        for (int ni = 0; ni < 4; ++ni)
            bfr[ni] = *reinterpret_cast<const frag*>(&Bs[b_rd + ni * 16 * LDT]);
        #pragma unroll
        for (int mi = 0; mi < 4; ++mi)
            #pragma unroll
            for (int ni = 0; ni < 4; ++ni)
                acc[mi][ni] = __builtin_amdgcn_mfma_f32_16x16x32_bf16(
                    af[mi], bfr[ni], acc[mi][ni], 0, 0, 0);
    }

    float* ob = out + (size_t)b * COUT * NSP;
    #pragma unroll
    for (int mi = 0; mi < 4; ++mi) {
        #pragma unroll
        for (int rg = 0; rg < 4; ++rg) {
            const int o = m0 + wm + mi * 16 + q * 4 + rg;
            const float bvv = (u_b[b * COUT + o] > PDROP) ? bias[o] : 0.f;
            float* orow = ob + (size_t)o * NSP + n0 + wn + l15;
            #pragma unroll
            for (int ni = 0; ni < 4; ++ni)
                orow[ni * 16] = acc[mi][ni][rg] + bvv;
        }
    }
}

extern "C" void kernel_launch(void* const* d_in, const int* in_sizes, int n_in,
                              void* d_out, int out_size, void* d_ws, size_t ws_size,
                              hipStream_t stream)
{
    const float* x      = (const float*)d_in[0];
    const float* weight = (const float*)d_in[1];
    const float* bias   = (const float*)d_in[2];
    const float* u_w    = (const float*)d_in[3];
    const float* u_b    = (const float*)d_in[4];
    float* out = (float*)d_out;

    const size_t wt_bytes = (size_t)BATCH * COUT * KTOT * sizeof(unsigned short); // 18.87 MB
    const size_t xt_bytes = (size_t)BATCH * NSP * CIN * sizeof(unsigned short);   // 33.55 MB
    dim3 grid(NSP / 128, COUT / 128, BATCH);   // 32 x 2 x 32 = 2048 blocks

    if (ws_size >= wt_bytes + xt_bytes) {
        unsigned short* wtp = (unsigned short*)d_ws;
        unsigned short* xtp = (unsigned short*)((char*)d_ws + wt_bytes);
        prepass<<<1024 + 2048, 256, 0, stream>>>(weight, u_w, x, wtp, xtp);
        conv_v5<<<grid, 256, 0, stream>>>(wtp, xtp, bias, u_b, out);
    } else {
        conv_fb<<<grid, 256, 0, stream>>>(x, weight, bias, u_w, u_b, out);
    }
}